// Round 4
// baseline (227.731 us; speedup 1.0000x reference)
//
#include <hip/hip_runtime.h>
#include <math.h>

#define D_IN 512
#define D_HID 128
#define D_OUT 512
#define N_ENT 262144

#define K3_BLOCKS 2048
#define WAVES_PER_BLOCK 4
#define TOTAL_WAVES (K3_BLOCKS * WAVES_PER_BLOCK)   // 8192
#define ROWS_PER_WAVE (N_ENT / TOTAL_WAVES)         // 32

// ws float-offsets
#define KV_OFF    0                // 512 floats: kvec pre-scaled by 1/sqrt(H)
#define BM_OFF    512              // 2048 block maxes
#define BS_OFF    2560             // 2048 block sums
#define BT5_OFF_F 4608             // byte 18432 (8B aligned): 2048*5 u64 keys
#define CNT_F     25088            // 1 int: last-block counter
#define WN_OFF    25092            // 5 floats: normalized top5 weights
#define SELI_F    25097            // 5 ints: top5 indices
#define WSUM_OFF  25102            // 1 float: sum of top5 weights

#define INV_SQRT_H 0.08838834764831845f  // 1/sqrt(128)

typedef float f32x4 __attribute__((ext_vector_type(4)));
typedef unsigned long long u64;

__device__ inline u64 pack_key(float v, int idx) {
    unsigned u = __float_as_uint(v);
    u = (u & 0x80000000u) ? ~u : (u | 0x80000000u);   // order-preserving
    return ((u64)u << 32) | (unsigned)(~idx);          // ties -> smaller idx wins
}
__device__ inline float unpack_val(u64 k) {
    unsigned o = (unsigned)(k >> 32);
    unsigned u = (o & 0x80000000u) ? (o & 0x7FFFFFFFu) : ~o;
    return __uint_as_float(u);
}
__device__ inline int unpack_idx(u64 k) { return (int)~(unsigned)(k & 0xFFFFFFFFu); }

#define INS5(kk) do { u64 _k = (kk); if (_k > t4) {            \
    if (_k > t0)      { t4=t3;t3=t2;t2=t1;t1=t0;t0=_k; }       \
    else if (_k > t1) { t4=t3;t3=t2;t2=t1;t1=_k; }             \
    else if (_k > t2) { t4=t3;t3=t2;t2=_k; }                   \
    else if (_k > t3) { t4=t3;t3=_k; }                         \
    else              { t4=_k; } } } while (0)

// ---------- K1: fused q = Wq@c+bq (redundant/block) + kvec chunk ----------
__global__ __launch_bounds__(256) void k_front(const float* __restrict__ c,
        const float* __restrict__ Wq, const float* __restrict__ bq,
        const float* __restrict__ Wk, float* __restrict__ ws) {
    __shared__ float qpart[256];
    __shared__ float qs[D_HID];
    __shared__ float kpart[4][64];
    const int t = threadIdx.x;
    if (blockIdx.x == 0 && t == 0) ((int*)ws)[CNT_F] = 0;   // reset last-block counter
    {   // phase 1: q[128], 2 threads per h
        const int h = t >> 1, half = t & 1;
        const f32x4* wq = (const f32x4*)(Wq + (h << 9) + (half << 8));
        const f32x4* cv = (const f32x4*)(c + (half << 8));
        float acc = 0.f;
        #pragma unroll 8
        for (int j = 0; j < 64; ++j) {
            f32x4 a = wq[j], b = cv[j];
            acc += a.x*b.x + a.y*b.y + a.z*b.z + a.w*b.w;
        }
        qpart[t] = acc;
    }
    __syncthreads();
    if (t < D_HID) qs[t] = qpart[2*t] + qpart[2*t+1] + bq[t];
    __syncthreads();
    {   // phase 2: kvec[d0..d0+64), wave g covers h in [32g,32g+32)
        const int g = t >> 6, d = t & 63;
        const int d0 = blockIdx.x * 64;
        const float* col = Wk + (size_t)(g * 32) * D_IN + d0 + d;
        float acc = 0.f;
        #pragma unroll 8
        for (int h = 0; h < 32; ++h) acc += col[(size_t)h * D_IN] * qs[g*32 + h];
        kpart[g][d] = acc;
    }
    __syncthreads();
    if (t < 64) {
        float kv = kpart[0][t] + kpart[1][t] + kpart[2][t] + kpart[3][t];
        ws[KV_OFF + blockIdx.x*64 + t] = kv * INV_SQRT_H;   // pre-scale
    }
}

// ---------- K2: logits + online softmax + per-block top5 + last-block grid merge ----------
__global__ __launch_bounds__(256) void k_logits(const float* __restrict__ E,
                                                float* __restrict__ ws) {
    const int t = threadIdx.x;
    const int l = t & 63;
    const int w = t >> 6;
    const int wg = blockIdx.x * WAVES_PER_BLOCK + w;
    const long row0 = (long)wg * ROWS_PER_WAVE;

    const f32x4* kv = (const f32x4*)(ws + KV_OFF);
    const f32x4 k0 = kv[l], k1 = kv[64 + l];

    float m = -INFINITY, s = 0.f;
    u64 t0 = 0, t1 = 0, t2 = 0, t3 = 0, t4 = 0;   // 0 < any real key

    for (int it = 0; it < ROWS_PER_WAVE; it += 2) {
        const f32x4* r0 = (const f32x4*)(E + (row0 + it)     * (long)D_IN);
        const f32x4* r1 = (const f32x4*)(E + (row0 + it + 1) * (long)D_IN);
        f32x4 a0 = __builtin_nontemporal_load(r0 + l);
        f32x4 a1 = __builtin_nontemporal_load(r0 + 64 + l);
        f32x4 b0 = __builtin_nontemporal_load(r1 + l);
        f32x4 b1 = __builtin_nontemporal_load(r1 + 64 + l);
        float d0 = a0.x*k0.x + a0.y*k0.y + a0.z*k0.z + a0.w*k0.w
                 + a1.x*k1.x + a1.y*k1.y + a1.z*k1.z + a1.w*k1.w;
        float d1 = b0.x*k0.x + b0.y*k0.y + b0.z*k0.z + b0.w*k0.w
                 + b1.x*k1.x + b1.y*k1.y + b1.z*k1.z + b1.w*k1.w;
        #pragma unroll
        for (int mm = 32; mm > 0; mm >>= 1) {   // two independent chains, ILP
            d0 += __shfl_xor(d0, mm, 64);
            d1 += __shfl_xor(d1, mm, 64);
        }
        // kvec pre-scaled: d0/d1 ARE the logits
        float nm = fmaxf(m, fmaxf(d0, d1));
        s = s * __expf(m - nm) + __expf(d0 - nm) + __expf(d1 - nm);
        m = nm;
        INS5(pack_key(d0, (int)row0 + it));
        INS5(pack_key(d1, (int)row0 + it + 1));
    }

    __shared__ float sm[WAVES_PER_BLOCK], ss[WAVES_PER_BLOCK];
    __shared__ u64 skey[WAVES_PER_BLOCK][5];
    if (l == 0) {
        sm[w] = m; ss[w] = s;
        skey[w][0]=t0; skey[w][1]=t1; skey[w][2]=t2; skey[w][3]=t3; skey[w][4]=t4;
    }
    __syncthreads();
    if (t == 0) {
        float M = fmaxf(fmaxf(sm[0], sm[1]), fmaxf(sm[2], sm[3]));
        float S = ss[0]*__expf(sm[0]-M) + ss[1]*__expf(sm[1]-M)
                + ss[2]*__expf(sm[2]-M) + ss[3]*__expf(sm[3]-M);
        u64 t0=0,t1=0,t2=0,t3=0,t4=0;
        #pragma unroll
        for (int j = 0; j < WAVES_PER_BLOCK*5; ++j) INS5(skey[j/5][j%5]);
        const int b = blockIdx.x;
        ws[BM_OFF + b] = M;
        ws[BS_OFF + b] = S;
        u64* bt = (u64*)ws + (BT5_OFF_F/2) + (size_t)b * 5;
        bt[0]=t0; bt[1]=t1; bt[2]=t2; bt[3]=t3; bt[4]=t4;
    }

    // ---- last-block grid merge (release: fence+atomic; acquire: atomic+fence) ----
    __shared__ int s_old;
    if (t == 0) {
        __threadfence();
        s_old = atomicAdd((int*)ws + CNT_F, 1);
    }
    __syncthreads();
    if (s_old != K3_BLOCKS - 1) return;
    __threadfence();

    __shared__ u64   mwc[WAVES_PER_BLOCK][5];
    __shared__ float selv_sh[5];
    __shared__ int   seli_sh[5];
    __shared__ float zp[WAVES_PER_BLOCK];
    const u64* cand = (const u64*)ws + (BT5_OFF_F/2);

    // per-thread top5 over 40 candidates each (10240 total)
    t0 = 0; t1 = 0; t2 = 0; t3 = 0; t4 = 0;
    #pragma unroll 8
    for (int j = 0; j < 40; ++j) INS5(cand[t + 256*j]);

    // wave top5: 5 rounds of extract-max (distinct keys -> exactly one advancer)
    {
        int pos = 0;
        u64 g0=0,g1=0,g2=0,g3=0,g4=0;
        #pragma unroll
        for (int r = 0; r < 5; ++r) {
            u64 head = pos==0?t0 : pos==1?t1 : pos==2?t2 : pos==3?t3 : pos==4?t4 : 0ULL;
            u64 wm = head;
            #pragma unroll
            for (int mm = 1; mm < 64; mm <<= 1) {
                u64 o = __shfl_xor(wm, mm, 64);
                wm = (o > wm) ? o : wm;
            }
            if (head == wm && wm != 0ULL) pos++;
            if (r==0) g0=wm; else if (r==1) g1=wm; else if (r==2) g2=wm;
            else if (r==3) g3=wm; else g4=wm;
        }
        if (l == 0) { mwc[w][0]=g0; mwc[w][1]=g1; mwc[w][2]=g2; mwc[w][3]=g3; mwc[w][4]=g4; }
    }
    __syncthreads();

    // cross-wave merge on wave 0 (lanes 0..3 present list heads)
    if (w == 0) {
        int pos = 0;
        #pragma unroll
        for (int r = 0; r < 5; ++r) {
            u64 head = (l < WAVES_PER_BLOCK && pos < 5) ? mwc[l][pos] : 0ULL;
            u64 wm = head;
            #pragma unroll
            for (int mm = 1; mm < 64; mm <<= 1) {
                u64 o = __shfl_xor(wm, mm, 64);
                wm = (o > wm) ? o : wm;
            }
            if (head == wm && wm != 0ULL) pos++;
            if (l == 0) { selv_sh[r] = unpack_val(wm); seli_sh[r] = unpack_idx(wm); }
        }
    }
    __syncthreads();

    const float M = selv_sh[0];   // global max logit == top-1 value

    // Z = sum_b S_b * exp(M_b - M)
    {
        float z = 0.f;
        #pragma unroll
        for (int k = 0; k < K3_BLOCKS/256; ++k) {
            int b = t + 256*k;
            z += ws[BS_OFF + b] * __expf(ws[BM_OFF + b] - M);
        }
        #pragma unroll
        for (int mm = 1; mm < 64; mm <<= 1) z += __shfl_xor(z, mm, 64);
        if (l == 0) zp[w] = z;
    }
    __syncthreads();
    if (t == 0) {
        float Z = zp[0] + zp[1] + zp[2] + zp[3];
        float wsum = 0.f;
        #pragma unroll
        for (int r = 0; r < 5; ++r) {
            float wv = __expf(selv_sh[r] - M) / Z;
            ws[WN_OFF + r] = wv;
            ((int*)ws)[SELI_F + r] = seli_sh[r];
            wsum += wv;
        }
        ws[WSUM_OFF] = wsum;
    }
}

// ---------- K3: fused u -> h -> out  (64 blocks x 256; weight reads distributed) ----------
__global__ __launch_bounds__(256) void k_vo(const float* __restrict__ E,
        const float* __restrict__ Wv, const float* __restrict__ bv,
        const float* __restrict__ Wo, const float* __restrict__ bo,
        const float* __restrict__ ws, float* __restrict__ out) {
    __shared__ float u_sh[D_IN];
    __shared__ float hp[256];
    __shared__ float h_sh[D_HID];
    const int t = threadIdx.x;
    const int l = t & 63;
    const int w = t >> 6;

    const float wn0 = ws[WN_OFF+0], wn1 = ws[WN_OFF+1], wn2 = ws[WN_OFF+2],
                wn3 = ws[WN_OFF+3], wn4 = ws[WN_OFF+4];
    const float Wsum = ws[WSUM_OFF];
    const int* seli = (const int*)ws + SELI_F;
    const long i0 = seli[0], i1 = seli[1], i2 = seli[2], i3 = seli[3], i4 = seli[4];

    // u[d] = sum_r wn_r * E[i_r][d]   (each thread: d = t, t+256)
    #pragma unroll
    for (int p = 0; p < 2; ++p) {
        const int d = t + p * 256;
        u_sh[d] = wn0 * E[i0*D_IN + d] + wn1 * E[i1*D_IN + d] + wn2 * E[i2*D_IN + d]
                + wn3 * E[i3*D_IN + d] + wn4 * E[i4*D_IN + d];
    }
    __syncthreads();

    // h[j] = Wv[j].u + Wsum*bv[j]   (2 threads per row, halves)
    {
        const int j = t >> 1, half = t & 1;
        const f32x4* wrow = (const f32x4*)(Wv + (size_t)j * D_IN + half * 256);
        const f32x4* uv   = (const f32x4*)(u_sh + half * 256);
        float acc = 0.f;
        #pragma unroll 8
        for (int k = 0; k < 64; ++k) {
            f32x4 a = wrow[k], b = uv[k];
            acc += a.x*b.x + a.y*b.y + a.z*b.z + a.w*b.w;
        }
        hp[t] = acc;
    }
    __syncthreads();
    if (t < D_HID) h_sh[t] = hp[2*t] + hp[2*t+1] + Wsum * bv[t];
    __syncthreads();

    // out: 8 rows per block (4 waves x 2 rows)
    {
        const float2* hv = (const float2*)h_sh;
        const float2 hh = hv[l];
        #pragma unroll
        for (int rr = 0; rr < 2; ++rr) {
            const int o = blockIdx.x * 8 + w * 2 + rr;
            const float2* orow = (const float2*)(Wo + (size_t)o * D_HID);
            float2 a = orow[l];
            float d = a.x*hh.x + a.y*hh.y;
            #pragma unroll
            for (int mm = 32; mm > 0; mm >>= 1) d += __shfl_xor(d, mm, 64);
            if (l == 0) out[o] = d + bo[o];
        }
    }
}

extern "C" void kernel_launch(void* const* d_in, const int* in_sizes, int n_in,
                              void* d_out, int out_size, void* d_ws, size_t ws_size,
                              hipStream_t stream) {
    const float* c  = (const float*)d_in[0];
    const float* E  = (const float*)d_in[1];
    const float* Wq = (const float*)d_in[2];
    const float* bq = (const float*)d_in[3];
    const float* Wk = (const float*)d_in[4];
    // d_in[5] = bk: uniform logit shift, cancels in softmax
    const float* Wv = (const float*)d_in[6];
    const float* bv = (const float*)d_in[7];
    const float* Wo = (const float*)d_in[8];
    const float* bo = (const float*)d_in[9];
    // d_in[10] = top_k (always 5)
    float* ws  = (float*)d_ws;
    float* out = (float*)d_out;

    hipLaunchKernelGGL(k_front,  dim3(8),         dim3(256), 0, stream, c, Wq, bq, Wk, ws);
    hipLaunchKernelGGL(k_logits, dim3(K3_BLOCKS), dim3(256), 0, stream, E, ws);
    hipLaunchKernelGGL(k_vo,     dim3(64),        dim3(256), 0, stream,
                       E, Wv, bv, Wo, bo, ws, out);
}

// Round 5
// 180.633 us; speedup vs baseline: 1.2607x; 1.2607x over previous
//
#include <hip/hip_runtime.h>
#include <math.h>

#define D_IN 512
#define D_HID 128
#define D_OUT 512
#define N_ENT 262144

#define K3_BLOCKS 2048
#define WAVES_PER_BLOCK 4
#define TOTAL_WAVES (K3_BLOCKS * WAVES_PER_BLOCK)   // 8192
#define ROWS_PER_WAVE (N_ENT / TOTAL_WAVES)         // 32

// Rows [0, ROW_RES) loaded with plain (cache-allocating) loads -> candidate
// Infinity-Cache residents across graph replays (224 MB of 256 MB L3).
// Rows >= ROW_RES streamed with nontemporal loads.
#define ROW_RES 114688

// ws float-offsets
#define KV_OFF    0                // 512: kvec pre-scaled by 1/sqrt(H)
#define Q_OFF     512              // 128: q vector
#define BM_OFF    640              // 2048 block maxes
#define BS_OFF    2688             // 2048 block sums
#define BT5_OFF_F 4736             // byte 18944 (8B aligned): 2048*5 u64 keys

#define INV_SQRT_H 0.08838834764831845f  // 1/sqrt(128)

typedef float f32x4 __attribute__((ext_vector_type(4)));
typedef unsigned long long u64;

__device__ inline u64 pack_key(float v, int idx) {
    unsigned u = __float_as_uint(v);
    u = (u & 0x80000000u) ? ~u : (u | 0x80000000u);   // order-preserving
    return ((u64)u << 32) | (unsigned)(~idx);          // ties -> smaller idx wins
}
__device__ inline float unpack_val(u64 k) {
    unsigned o = (unsigned)(k >> 32);
    unsigned u = (o & 0x80000000u) ? (o & 0x7FFFFFFFu) : ~o;
    return __uint_as_float(u);
}
__device__ inline int unpack_idx(u64 k) { return (int)~(unsigned)(k & 0xFFFFFFFFu); }

#define INS5(kk) do { u64 _k = (kk); if (_k > t4) {            \
    if (_k > t0)      { t4=t3;t3=t2;t2=t1;t1=t0;t0=_k; }       \
    else if (_k > t1) { t4=t3;t3=t2;t2=t1;t1=_k; }             \
    else if (_k > t2) { t4=t3;t3=t2;t2=_k; }                   \
    else if (_k > t3) { t4=t3;t3=_k; }                         \
    else              { t4=_k; } } } while (0)

// ---------- K1: q[h] = Wq[h].c + bq[h]   (128 blocks x 64) ----------
__global__ void k_q(const float* __restrict__ c, const float* __restrict__ Wq,
                    const float* __restrict__ bq, float* __restrict__ ws) {
    const int h = blockIdx.x;
    const int l = threadIdx.x;
    const f32x4* row = (const f32x4*)(Wq + (size_t)h * D_IN);
    const f32x4* cv  = (const f32x4*)c;
    f32x4 a0 = row[l], a1 = row[64 + l];
    f32x4 c0 = cv[l],  c1 = cv[64 + l];
    float d = a0.x*c0.x + a0.y*c0.y + a0.z*c0.z + a0.w*c0.w
            + a1.x*c1.x + a1.y*c1.y + a1.z*c1.z + a1.w*c1.w;
    #pragma unroll
    for (int m = 32; m > 0; m >>= 1) d += __shfl_xor(d, m, 64);
    if (l == 0) ws[Q_OFF + h] = d + bq[h];
}

// ---------- K2: kvec slice = Wk^T q (pre-scaled)  (8 blocks x 256) ----------
// (bk . q is a uniform logit shift -> cancels in softmax, dropped)
__global__ __launch_bounds__(256) void k_kvec(const float* __restrict__ Wk,
                                              float* __restrict__ ws) {
    __shared__ float qs[D_HID];
    __shared__ float kpart[4][64];
    const int t = threadIdx.x;
    if (t < D_HID) qs[t] = ws[Q_OFF + t];
    __syncthreads();
    const int g = t >> 6, d = t & 63;
    const int d0 = blockIdx.x * 64;
    const float* col = Wk + (size_t)(g * 32) * D_IN + d0 + d;
    float acc = 0.f;
    #pragma unroll 8
    for (int h = 0; h < 32; ++h) acc += col[(size_t)h * D_IN] * qs[g*32 + h];
    kpart[g][d] = acc;
    __syncthreads();
    if (t < 64) {
        float kv = kpart[0][t] + kpart[1][t] + kpart[2][t] + kpart[3][t];
        ws[KV_OFF + d0 + t] = kv * INV_SQRT_H;   // pre-scale
    }
}

// ---------- row scan helper (NT = nontemporal streaming half) ----------
template <bool NT>
__device__ __forceinline__ void scan_rows(const float* __restrict__ E, long row0,
        int l, f32x4 k0, f32x4 k1, float& m, float& s,
        u64& t0, u64& t1, u64& t2, u64& t3, u64& t4) {
    for (int it = 0; it < ROWS_PER_WAVE; it += 2) {
        const f32x4* r0 = (const f32x4*)(E + (row0 + it)     * (long)D_IN);
        const f32x4* r1 = (const f32x4*)(E + (row0 + it + 1) * (long)D_IN);
        f32x4 a0, a1, b0, b1;
        if (NT) {
            a0 = __builtin_nontemporal_load(r0 + l);
            a1 = __builtin_nontemporal_load(r0 + 64 + l);
            b0 = __builtin_nontemporal_load(r1 + l);
            b1 = __builtin_nontemporal_load(r1 + 64 + l);
        } else {
            a0 = r0[l]; a1 = r0[64 + l]; b0 = r1[l]; b1 = r1[64 + l];
        }
        float d0 = a0.x*k0.x + a0.y*k0.y + a0.z*k0.z + a0.w*k0.w
                 + a1.x*k1.x + a1.y*k1.y + a1.z*k1.z + a1.w*k1.w;
        float d1 = b0.x*k0.x + b0.y*k0.y + b0.z*k0.z + b0.w*k0.w
                 + b1.x*k1.x + b1.y*k1.y + b1.z*k1.z + b1.w*k1.w;
        #pragma unroll
        for (int mm = 32; mm > 0; mm >>= 1) {   // two independent chains, ILP
            d0 += __shfl_xor(d0, mm, 64);
            d1 += __shfl_xor(d1, mm, 64);
        }
        float nm = fmaxf(m, fmaxf(d0, d1));
        s = s * __expf(m - nm) + __expf(d0 - nm) + __expf(d1 - nm);
        m = nm;
        INS5(pack_key(d0, (int)row0 + it));
        INS5(pack_key(d1, (int)row0 + it + 1));
    }
}

// ---------- K3: logits + online softmax + per-block top5 ----------
__global__ __launch_bounds__(256) void k_logits(const float* __restrict__ E,
                                                float* __restrict__ ws) {
    const int t = threadIdx.x;
    const int l = t & 63;
    const int w = t >> 6;
    const int wg = blockIdx.x * WAVES_PER_BLOCK + w;
    const long row0 = (long)wg * ROWS_PER_WAVE;

    const f32x4* kv = (const f32x4*)(ws + KV_OFF);
    const f32x4 k0 = kv[l], k1 = kv[64 + l];

    float m = -INFINITY, s = 0.f;
    u64 t0 = 0, t1 = 0, t2 = 0, t3 = 0, t4 = 0;   // 0 < any real key

    if (row0 < ROW_RES)   // wave-uniform (row0 multiple of 32, boundary too)
        scan_rows<false>(E, row0, l, k0, k1, m, s, t0, t1, t2, t3, t4);
    else
        scan_rows<true>(E, row0, l, k0, k1, m, s, t0, t1, t2, t3, t4);

    __shared__ float sm[WAVES_PER_BLOCK], ss[WAVES_PER_BLOCK];
    __shared__ u64 skey[WAVES_PER_BLOCK][5];
    if (l == 0) {
        sm[w] = m; ss[w] = s;
        skey[w][0]=t0; skey[w][1]=t1; skey[w][2]=t2; skey[w][3]=t3; skey[w][4]=t4;
    }
    __syncthreads();
    if (t == 0) {
        float M = fmaxf(fmaxf(sm[0], sm[1]), fmaxf(sm[2], sm[3]));
        float S = ss[0]*__expf(sm[0]-M) + ss[1]*__expf(sm[1]-M)
                + ss[2]*__expf(sm[2]-M) + ss[3]*__expf(sm[3]-M);
        u64 t0=0,t1=0,t2=0,t3=0,t4=0;
        #pragma unroll
        for (int j = 0; j < WAVES_PER_BLOCK*5; ++j) INS5(skey[j/5][j%5]);
        const int b = blockIdx.x;
        ws[BM_OFF + b] = M;
        ws[BS_OFF + b] = S;
        u64* bt = (u64*)ws + (BT5_OFF_F/2) + (size_t)b * 5;
        bt[0]=t0; bt[1]=t1; bt[2]=t2; bt[3]=t3; bt[4]=t4;
    }
}

// ---------- K4: redundant merge + u -> h -> out  (64 blocks x 256) ----------
// Every block redundantly computes the (identical, deterministic) global
// top5/Z merge (~3us, fully parallel) -> no extra kernel, no fences, and the
// Wv/Wo reads stay distributed across 64 CUs.
__global__ __launch_bounds__(256) void k_vo(const float* __restrict__ E,
        const float* __restrict__ Wv, const float* __restrict__ bv,
        const float* __restrict__ Wo, const float* __restrict__ bo,
        const float* __restrict__ ws, float* __restrict__ out) {
    __shared__ u64   mwc[4][5];
    __shared__ float selv_sh[5];
    __shared__ int   seli_sh[5];
    __shared__ float wn_sh[5];
    __shared__ float zp[4];
    __shared__ float Wsum_sh;
    __shared__ float u_sh[D_IN];
    __shared__ float hp[256];
    __shared__ float h_sh[D_HID];
    const int t = threadIdx.x;
    const int l = t & 63;
    const int w = t >> 6;
    const u64* cand = (const u64*)ws + (BT5_OFF_F/2);

    // per-thread top5 over 40 candidates each (10240 total)
    u64 t0=0,t1=0,t2=0,t3=0,t4=0;
    #pragma unroll 8
    for (int j = 0; j < 40; ++j) INS5(cand[t + 256*j]);

    // wave top5: 5 rounds of extract-max (distinct keys -> exactly one advancer)
    {
        int pos = 0;
        u64 g0=0,g1=0,g2=0,g3=0,g4=0;
        #pragma unroll
        for (int r = 0; r < 5; ++r) {
            u64 head = pos==0?t0 : pos==1?t1 : pos==2?t2 : pos==3?t3 : pos==4?t4 : 0ULL;
            u64 wm = head;
            #pragma unroll
            for (int mm = 1; mm < 64; mm <<= 1) {
                u64 o = __shfl_xor(wm, mm, 64);
                wm = (o > wm) ? o : wm;
            }
            if (head == wm && wm != 0ULL) pos++;
            if (r==0) g0=wm; else if (r==1) g1=wm; else if (r==2) g2=wm;
            else if (r==3) g3=wm; else g4=wm;
        }
        if (l == 0) { mwc[w][0]=g0; mwc[w][1]=g1; mwc[w][2]=g2; mwc[w][3]=g3; mwc[w][4]=g4; }
    }
    __syncthreads();

    // cross-wave merge on wave 0 (lanes 0..3 present list heads)
    if (w == 0) {
        int pos = 0;
        #pragma unroll
        for (int r = 0; r < 5; ++r) {
            u64 head = (l < 4 && pos < 5) ? mwc[l][pos] : 0ULL;
            u64 wm = head;
            #pragma unroll
            for (int mm = 1; mm < 64; mm <<= 1) {
                u64 o = __shfl_xor(wm, mm, 64);
                wm = (o > wm) ? o : wm;
            }
            if (head == wm && wm != 0ULL) pos++;
            if (l == 0) { selv_sh[r] = unpack_val(wm); seli_sh[r] = unpack_idx(wm); }
        }
    }
    __syncthreads();

    const float M = selv_sh[0];   // global max logit == top-1 value

    // Z = sum_b S_b * exp(M_b - M)
    {
        float z = 0.f;
        #pragma unroll
        for (int k = 0; k < K3_BLOCKS/256; ++k) {
            int b = t + 256*k;
            z += ws[BS_OFF + b] * __expf(ws[BM_OFF + b] - M);
        }
        #pragma unroll
        for (int mm = 1; mm < 64; mm <<= 1) z += __shfl_xor(z, mm, 64);
        if (l == 0) zp[w] = z;
    }
    __syncthreads();
    if (t == 0) {
        float Z = zp[0] + zp[1] + zp[2] + zp[3];
        float wsum = 0.f;
        #pragma unroll
        for (int r = 0; r < 5; ++r) {
            float wv = __expf(selv_sh[r] - M) / Z;
            wn_sh[r] = wv;
            wsum += wv;
        }
        Wsum_sh = wsum;
    }
    __syncthreads();

    const float wn0 = wn_sh[0], wn1 = wn_sh[1], wn2 = wn_sh[2],
                wn3 = wn_sh[3], wn4 = wn_sh[4];
    const long i0 = seli_sh[0], i1 = seli_sh[1], i2 = seli_sh[2],
               i3 = seli_sh[3], i4 = seli_sh[4];

    // u[d] = sum_r wn_r * E[i_r][d]
    #pragma unroll
    for (int p = 0; p < 2; ++p) {
        const int d = t + p * 256;
        u_sh[d] = wn0 * E[i0*D_IN + d] + wn1 * E[i1*D_IN + d] + wn2 * E[i2*D_IN + d]
                + wn3 * E[i3*D_IN + d] + wn4 * E[i4*D_IN + d];
    }
    __syncthreads();

    // h[j] = Wv[j].u + Wsum*bv[j]   (2 threads per row, halves)
    {
        const int j = t >> 1, half = t & 1;
        const f32x4* wrow = (const f32x4*)(Wv + (size_t)j * D_IN + half * 256);
        const f32x4* uv   = (const f32x4*)(u_sh + half * 256);
        float acc = 0.f;
        #pragma unroll 8
        for (int k = 0; k < 64; ++k) {
            f32x4 a = wrow[k], b = uv[k];
            acc += a.x*b.x + a.y*b.y + a.z*b.z + a.w*b.w;
        }
        hp[t] = acc;
    }
    __syncthreads();
    if (t < D_HID) h_sh[t] = hp[2*t] + hp[2*t+1] + Wsum_sh * bv[t];
    __syncthreads();

    // out: 8 rows per block (4 waves x 2 rows)
    {
        const float2* hv = (const float2*)h_sh;
        const float2 hh = hv[l];
        #pragma unroll
        for (int rr = 0; rr < 2; ++rr) {
            const int o = blockIdx.x * 8 + w * 2 + rr;
            const float2* orow = (const float2*)(Wo + (size_t)o * D_HID);
            float2 a = orow[l];
            float d = a.x*hh.x + a.y*hh.y;
            #pragma unroll
            for (int mm = 32; mm > 0; mm >>= 1) d += __shfl_xor(d, mm, 64);
            if (l == 0) out[o] = d + bo[o];
        }
    }
}

extern "C" void kernel_launch(void* const* d_in, const int* in_sizes, int n_in,
                              void* d_out, int out_size, void* d_ws, size_t ws_size,
                              hipStream_t stream) {
    const float* c  = (const float*)d_in[0];
    const float* E  = (const float*)d_in[1];
    const float* Wq = (const float*)d_in[2];
    const float* bq = (const float*)d_in[3];
    const float* Wk = (const float*)d_in[4];
    // d_in[5] = bk: uniform logit shift, cancels in softmax
    const float* Wv = (const float*)d_in[6];
    const float* bv = (const float*)d_in[7];
    const float* Wo = (const float*)d_in[8];
    const float* bo = (const float*)d_in[9];
    // d_in[10] = top_k (always 5)
    float* ws  = (float*)d_ws;
    float* out = (float*)d_out;

    hipLaunchKernelGGL(k_q,      dim3(128),       dim3(64),  0, stream, c, Wq, bq, ws);
    hipLaunchKernelGGL(k_kvec,   dim3(8),         dim3(256), 0, stream, Wk, ws);
    hipLaunchKernelGGL(k_logits, dim3(K3_BLOCKS), dim3(256), 0, stream, E, ws);
    hipLaunchKernelGGL(k_vo,     dim3(64),        dim3(256), 0, stream,
                       E, Wv, bv, Wo, bo, ws, out);
}

// Round 6
// 127.751 us; speedup vs baseline: 1.7826x; 1.4139x over previous
//
#include <hip/hip_runtime.h>
#include <math.h>

#define D_IN 512
#define D_HID 128
#define D_OUT 512
#define N_ENT 262144

#define K3_BLOCKS 2048
#define WAVES_PER_BLOCK 4
#define TOTAL_WAVES (K3_BLOCKS * WAVES_PER_BLOCK)   // 8192
#define ROWS_PER_WAVE (N_ENT / TOTAL_WAVES)         // 32

// ws float-offsets
#define KV_OFF    0                // 512: kvec pre-scaled by 1/sqrt(H)
#define Q_OFF     512              // 128: q vector
#define BM_OFF    640              // 2048 block maxes
#define BS_OFF    2688             // 2048 block sums
#define BT5_OFF_F 4736             // byte 18944 (8B aligned): 2048*5 u64 keys

#define INV_SQRT_H 0.08838834764831845f  // 1/sqrt(128)

typedef float f32x4 __attribute__((ext_vector_type(4)));
typedef unsigned long long u64;

__device__ inline u64 pack_key(float v, int idx) {
    unsigned u = __float_as_uint(v);
    u = (u & 0x80000000u) ? ~u : (u | 0x80000000u);   // order-preserving
    return ((u64)u << 32) | (unsigned)(~idx);          // ties -> smaller idx wins
}
__device__ inline float unpack_val(u64 k) {
    unsigned o = (unsigned)(k >> 32);
    unsigned u = (o & 0x80000000u) ? (o & 0x7FFFFFFFu) : ~o;
    return __uint_as_float(u);
}
__device__ inline int unpack_idx(u64 k) { return (int)~(unsigned)(k & 0xFFFFFFFFu); }

#define INS5(kk) do { u64 _k = (kk); if (_k > t4) {            \
    if (_k > t0)      { t4=t3;t3=t2;t2=t1;t1=t0;t0=_k; }       \
    else if (_k > t1) { t4=t3;t3=t2;t2=t1;t1=_k; }             \
    else if (_k > t2) { t4=t3;t3=t2;t2=_k; }                   \
    else if (_k > t3) { t4=t3;t3=_k; }                         \
    else              { t4=_k; } } } while (0)

// ---------- K1: q[h] = Wq[h].c + bq[h]   (128 blocks x 64) ----------
__global__ void k_q(const float* __restrict__ c, const float* __restrict__ Wq,
                    const float* __restrict__ bq, float* __restrict__ ws) {
    const int h = blockIdx.x;
    const int l = threadIdx.x;
    const f32x4* row = (const f32x4*)(Wq + (size_t)h * D_IN);
    const f32x4* cv  = (const f32x4*)c;
    f32x4 a0 = row[l], a1 = row[64 + l];
    f32x4 c0 = cv[l],  c1 = cv[64 + l];
    float d = a0.x*c0.x + a0.y*c0.y + a0.z*c0.z + a0.w*c0.w
            + a1.x*c1.x + a1.y*c1.y + a1.z*c1.z + a1.w*c1.w;
    #pragma unroll
    for (int m = 32; m > 0; m >>= 1) d += __shfl_xor(d, m, 64);
    if (l == 0) ws[Q_OFF + h] = d + bq[h];
}

// ---------- K2: kvec slice = Wk^T q (pre-scaled)  (8 blocks x 256) ----------
// (bk . q is a uniform logit shift -> cancels in softmax, dropped)
__global__ __launch_bounds__(256) void k_kvec(const float* __restrict__ Wk,
                                              float* __restrict__ ws) {
    __shared__ float qs[D_HID];
    __shared__ float kpart[4][64];
    const int t = threadIdx.x;
    if (t < D_HID) qs[t] = ws[Q_OFF + t];
    __syncthreads();
    const int g = t >> 6, d = t & 63;
    const int d0 = blockIdx.x * 64;
    const float* col = Wk + (size_t)(g * 32) * D_IN + d0 + d;
    float acc = 0.f;
    #pragma unroll 8
    for (int h = 0; h < 32; ++h) acc += col[(size_t)h * D_IN] * qs[g*32 + h];
    kpart[g][d] = acc;
    __syncthreads();
    if (t < 64) {
        float kv = kpart[0][t] + kpart[1][t] + kpart[2][t] + kpart[3][t];
        ws[KV_OFF + d0 + t] = kv * INV_SQRT_H;   // pre-scale
    }
}

// ---------- K3: logits + online softmax + per-block top5 (all-NT stream) ----------
__global__ __launch_bounds__(256) void k_logits(const float* __restrict__ E,
                                                float* __restrict__ ws) {
    const int t = threadIdx.x;
    const int l = t & 63;
    const int w = t >> 6;
    const int wg = blockIdx.x * WAVES_PER_BLOCK + w;
    const long row0 = (long)wg * ROWS_PER_WAVE;

    const f32x4* kv = (const f32x4*)(ws + KV_OFF);
    const f32x4 k0 = kv[l], k1 = kv[64 + l];

    float m = -INFINITY, s = 0.f;
    u64 t0 = 0, t1 = 0, t2 = 0, t3 = 0, t4 = 0;   // 0 < any real key

    for (int it = 0; it < ROWS_PER_WAVE; it += 2) {
        const f32x4* r0 = (const f32x4*)(E + (row0 + it)     * (long)D_IN);
        const f32x4* r1 = (const f32x4*)(E + (row0 + it + 1) * (long)D_IN);
        f32x4 a0 = __builtin_nontemporal_load(r0 + l);
        f32x4 a1 = __builtin_nontemporal_load(r0 + 64 + l);
        f32x4 b0 = __builtin_nontemporal_load(r1 + l);
        f32x4 b1 = __builtin_nontemporal_load(r1 + 64 + l);
        float d0 = a0.x*k0.x + a0.y*k0.y + a0.z*k0.z + a0.w*k0.w
                 + a1.x*k1.x + a1.y*k1.y + a1.z*k1.z + a1.w*k1.w;
        float d1 = b0.x*k0.x + b0.y*k0.y + b0.z*k0.z + b0.w*k0.w
                 + b1.x*k1.x + b1.y*k1.y + b1.z*k1.z + b1.w*k1.w;
        #pragma unroll
        for (int mm = 32; mm > 0; mm >>= 1) {   // two independent chains, ILP
            d0 += __shfl_xor(d0, mm, 64);
            d1 += __shfl_xor(d1, mm, 64);
        }
        // kvec pre-scaled: d0/d1 ARE the logits
        float nm = fmaxf(m, fmaxf(d0, d1));
        s = s * __expf(m - nm) + __expf(d0 - nm) + __expf(d1 - nm);
        m = nm;
        INS5(pack_key(d0, (int)row0 + it));
        INS5(pack_key(d1, (int)row0 + it + 1));
    }

    __shared__ float sm[WAVES_PER_BLOCK], ss[WAVES_PER_BLOCK];
    __shared__ u64 skey[WAVES_PER_BLOCK][5];
    if (l == 0) {
        sm[w] = m; ss[w] = s;
        skey[w][0]=t0; skey[w][1]=t1; skey[w][2]=t2; skey[w][3]=t3; skey[w][4]=t4;
    }
    __syncthreads();
    if (t == 0) {
        float M = fmaxf(fmaxf(sm[0], sm[1]), fmaxf(sm[2], sm[3]));
        float S = ss[0]*__expf(sm[0]-M) + ss[1]*__expf(sm[1]-M)
                + ss[2]*__expf(sm[2]-M) + ss[3]*__expf(sm[3]-M);
        u64 t0=0,t1=0,t2=0,t3=0,t4=0;
        #pragma unroll
        for (int j = 0; j < WAVES_PER_BLOCK*5; ++j) INS5(skey[j/5][j%5]);
        const int b = blockIdx.x;
        ws[BM_OFF + b] = M;
        ws[BS_OFF + b] = S;
        u64* bt = (u64*)ws + (BT5_OFF_F/2) + (size_t)b * 5;
        bt[0]=t0; bt[1]=t1; bt[2]=t2; bt[3]=t3; bt[4]=t4;
    }
}

// ---------- K4: redundant merge + u -> h -> out  (64 blocks x 256) ----------
// Every block redundantly computes the (identical, deterministic) global
// top5/Z merge (~3us, fully parallel) -> no extra kernel, no fences, and the
// Wv/Wo reads stay distributed across 64 CUs.
__global__ __launch_bounds__(256) void k_vo(const float* __restrict__ E,
        const float* __restrict__ Wv, const float* __restrict__ bv,
        const float* __restrict__ Wo, const float* __restrict__ bo,
        const float* __restrict__ ws, float* __restrict__ out) {
    __shared__ u64   mwc[4][5];
    __shared__ float selv_sh[5];
    __shared__ int   seli_sh[5];
    __shared__ float wn_sh[5];
    __shared__ float zp[4];
    __shared__ float Wsum_sh;
    __shared__ float u_sh[D_IN];
    __shared__ float hp[256];
    __shared__ float h_sh[D_HID];
    const int t = threadIdx.x;
    const int l = t & 63;
    const int w = t >> 6;
    const u64* cand = (const u64*)ws + (BT5_OFF_F/2);

    // per-thread top5 over 40 candidates each (10240 total)
    u64 t0=0,t1=0,t2=0,t3=0,t4=0;
    #pragma unroll 8
    for (int j = 0; j < 40; ++j) INS5(cand[t + 256*j]);

    // wave top5: 5 rounds of extract-max (distinct keys -> exactly one advancer)
    {
        int pos = 0;
        u64 g0=0,g1=0,g2=0,g3=0,g4=0;
        #pragma unroll
        for (int r = 0; r < 5; ++r) {
            u64 head = pos==0?t0 : pos==1?t1 : pos==2?t2 : pos==3?t3 : pos==4?t4 : 0ULL;
            u64 wm = head;
            #pragma unroll
            for (int mm = 1; mm < 64; mm <<= 1) {
                u64 o = __shfl_xor(wm, mm, 64);
                wm = (o > wm) ? o : wm;
            }
            if (head == wm && wm != 0ULL) pos++;
            if (r==0) g0=wm; else if (r==1) g1=wm; else if (r==2) g2=wm;
            else if (r==3) g3=wm; else g4=wm;
        }
        if (l == 0) { mwc[w][0]=g0; mwc[w][1]=g1; mwc[w][2]=g2; mwc[w][3]=g3; mwc[w][4]=g4; }
    }
    __syncthreads();

    // cross-wave merge on wave 0 (lanes 0..3 present list heads)
    if (w == 0) {
        int pos = 0;
        #pragma unroll
        for (int r = 0; r < 5; ++r) {
            u64 head = (l < 4 && pos < 5) ? mwc[l][pos] : 0ULL;
            u64 wm = head;
            #pragma unroll
            for (int mm = 1; mm < 64; mm <<= 1) {
                u64 o = __shfl_xor(wm, mm, 64);
                wm = (o > wm) ? o : wm;
            }
            if (head == wm && wm != 0ULL) pos++;
            if (l == 0) { selv_sh[r] = unpack_val(wm); seli_sh[r] = unpack_idx(wm); }
        }
    }
    __syncthreads();

    const float M = selv_sh[0];   // global max logit == top-1 value

    // Z = sum_b S_b * exp(M_b - M)
    {
        float z = 0.f;
        #pragma unroll
        for (int k = 0; k < K3_BLOCKS/256; ++k) {
            int b = t + 256*k;
            z += ws[BS_OFF + b] * __expf(ws[BM_OFF + b] - M);
        }
        #pragma unroll
        for (int mm = 1; mm < 64; mm <<= 1) z += __shfl_xor(z, mm, 64);
        if (l == 0) zp[w] = z;
    }
    __syncthreads();
    if (t == 0) {
        float Z = zp[0] + zp[1] + zp[2] + zp[3];
        float wsum = 0.f;
        #pragma unroll
        for (int r = 0; r < 5; ++r) {
            float wv = __expf(selv_sh[r] - M) / Z;
            wn_sh[r] = wv;
            wsum += wv;
        }
        Wsum_sh = wsum;
    }
    __syncthreads();

    const float wn0 = wn_sh[0], wn1 = wn_sh[1], wn2 = wn_sh[2],
                wn3 = wn_sh[3], wn4 = wn_sh[4];
    const long i0 = seli_sh[0], i1 = seli_sh[1], i2 = seli_sh[2],
               i3 = seli_sh[3], i4 = seli_sh[4];

    // u[d] = sum_r wn_r * E[i_r][d]
    #pragma unroll
    for (int p = 0; p < 2; ++p) {
        const int d = t + p * 256;
        u_sh[d] = wn0 * E[i0*D_IN + d] + wn1 * E[i1*D_IN + d] + wn2 * E[i2*D_IN + d]
                + wn3 * E[i3*D_IN + d] + wn4 * E[i4*D_IN + d];
    }
    __syncthreads();

    // h[j] = Wv[j].u + Wsum*bv[j]   (2 threads per row, halves)
    {
        const int j = t >> 1, half = t & 1;
        const f32x4* wrow = (const f32x4*)(Wv + (size_t)j * D_IN + half * 256);
        const f32x4* uv   = (const f32x4*)(u_sh + half * 256);
        float acc = 0.f;
        #pragma unroll 8
        for (int k = 0; k < 64; ++k) {
            f32x4 a = wrow[k], b = uv[k];
            acc += a.x*b.x + a.y*b.y + a.z*b.z + a.w*b.w;
        }
        hp[t] = acc;
    }
    __syncthreads();
    if (t < D_HID) h_sh[t] = hp[2*t] + hp[2*t+1] + Wsum_sh * bv[t];
    __syncthreads();

    // out: 8 rows per block (4 waves x 2 rows)
    {
        const float2* hv = (const float2*)h_sh;
        const float2 hh = hv[l];
        #pragma unroll
        for (int rr = 0; rr < 2; ++rr) {
            const int o = blockIdx.x * 8 + w * 2 + rr;
            const float2* orow = (const float2*)(Wo + (size_t)o * D_HID);
            float2 a = orow[l];
            float d = a.x*hh.x + a.y*hh.y;
            #pragma unroll
            for (int mm = 32; mm > 0; mm >>= 1) d += __shfl_xor(d, mm, 64);
            if (l == 0) out[o] = d + bo[o];
        }
    }
}

extern "C" void kernel_launch(void* const* d_in, const int* in_sizes, int n_in,
                              void* d_out, int out_size, void* d_ws, size_t ws_size,
                              hipStream_t stream) {
    const float* c  = (const float*)d_in[0];
    const float* E  = (const float*)d_in[1];
    const float* Wq = (const float*)d_in[2];
    const float* bq = (const float*)d_in[3];
    const float* Wk = (const float*)d_in[4];
    // d_in[5] = bk: uniform logit shift, cancels in softmax
    const float* Wv = (const float*)d_in[6];
    const float* bv = (const float*)d_in[7];
    const float* Wo = (const float*)d_in[8];
    const float* bo = (const float*)d_in[9];
    // d_in[10] = top_k (always 5)
    float* ws  = (float*)d_ws;
    float* out = (float*)d_out;

    hipLaunchKernelGGL(k_q,      dim3(128),       dim3(64),  0, stream, c, Wq, bq, ws);
    hipLaunchKernelGGL(k_kvec,   dim3(8),         dim3(256), 0, stream, Wk, ws);
    hipLaunchKernelGGL(k_logits, dim3(K3_BLOCKS), dim3(256), 0, stream, E, ws);
    hipLaunchKernelGGL(k_vo,     dim3(64),        dim3(256), 0, stream,
                       E, Wv, bv, Wo, bo, ws, out);
}